// Round 7
// baseline (1101.334 us; speedup 1.0000x reference)
//
#include <hip/hip_runtime.h>
#include <hip/hip_bf16.h>
#include <hip/hip_cooperative_groups.h>
#include <math.h>

namespace cg = cooperative_groups;

#define LSEQ 2048
#define HD   512
#define NST  32
#define LC   32
#define NCHK 64   /* LSEQ/LC */
#define SUP  8    /* chunks per superchunk */
#define NSUP 8    /* NCHK/SUP */
#define HH   (HD * HD)
#define GRID 256
#define BLK  256
#define NTH  (GRID * BLK)   /* 65536 */

typedef __bf16 bf16;
typedef __bf16 bf16x8 __attribute__((ext_vector_type(8)));
typedef float  floatx4 __attribute__((ext_vector_type(4)));

__device__ __forceinline__ float wave_reduce_add(float v) {
#pragma unroll
    for (int m = 32; m; m >>= 1) v += __shfl_xor(v, m, 64);
    return v;
}

__device__ __forceinline__ float gelu_tanh(float x) {
    float z = 0.7978845608028654f * (x + 0.044715f * x * x * x);
    float e = __expf(2.f * z);
    float th = 1.f - 2.f / (e + 1.f);   // tanh(z), saturates cleanly at e=inf
    return 0.5f * x * (1.f + th);
}

__device__ __forceinline__ void make_ab(float lre, float lim, float step,
                                        float br0, float bi0,
                                        float& ar, float& ai, float& br, float& bi) {
    float s2 = 0.5f * step;
    float dr = 1.f - s2 * lre, di = -s2 * lim;      // 1 - (dt/2)Lam
    float inv = 1.f / (dr * dr + di * di);
    float blr = dr * inv, bli = -di * inv;          // BL = 1/(dr+i*di)
    float nr = 1.f + s2 * lre, ni = s2 * lim;       // 1 + (dt/2)Lam
    ar = blr * nr - bli * ni;
    ai = blr * ni + bli * nr;
    float tr = step * br0, ti = step * bi0;         // dt * B
    br = blr * tr - bli * ti;
    bi = blr * ti + bli * tr;
}

// ==========================================================================
// Fused cooperative kernel: 256 blocks x 256 threads (1 block/CU guaranteed)
// ==========================================================================
__global__ __launch_bounds__(BLK, 1) void fused_kernel(
    const float* __restrict__ x,   const float* __restrict__ ew,
    const float* __restrict__ eb,  const float* __restrict__ dw,
    const float* __restrict__ db,  const float* __restrict__ nw,
    const float* __restrict__ nb,  const float* __restrict__ lre,
    const float* __restrict__ lim, const float* __restrict__ bre,
    const float* __restrict__ bim, const float* __restrict__ cre,
    const float* __restrict__ cim, const float* __restrict__ dd,
    const float* __restrict__ ls,  const float* __restrict__ ow,
    const float* __restrict__ ob,  const float* __restrict__ o2w,
    const float* __restrict__ o2b, float* __restrict__ out,
    char* __restrict__ ws)
{
    cg::grid_group grid = cg::this_grid();

    float*  h     = (float*)ws;                         // 4 MB [L][HD]
    float2* f     = (float2*)(ws + (4  << 20));         // 8 MB [NCHK][NST][HD]
    float2* f2    = (float2*)(ws + (12 << 20));         // 8 MB corrected prefixes
    bf16*   g     = (bf16*)(ws + (20 << 20));           // 2 MB [L][HD]
    bf16*   wb    = (bf16*)(ws + (22 << 20));           // 4 MB bf16 weights
    float2* stats = (float2*)(ws + (26 << 20));         // 16 KB (m, rstd) per row
    float2* cA    = (float2*)(ws + (26 << 20) + (64 << 10));  // 4x 512 KB
    float2* cB    = cA + 4 * NST * HD;
    float2* cC    = cB + 4 * NST * HD;
    float2* cAp   = cC + 4 * NST * HD;

    const int bid = blockIdx.x, tid = threadIdx.x;
    const int tg  = bid * BLK + tid;                    // 0..65535
    const int lane = tid & 63, wv = tid >> 6;

    __shared__ float  tile[4096];   // 256 t-rows x 16 ch (16 KB)
    __shared__ float2 sst[256];
    __shared__ float  snw[16], snb[16];

    // ================= INIT: coeff prep + weight cvt + encoder =================
    {
        // 65536 threads == 4*HD*NST exactly
        int lay = tg >> 14, rem = tg & 16383;
        int ch = rem >> 5, n = rem & 31;
        float step = __expf(ls[lay * HD + ch]);
        float ar, ai, br, bi;
        make_ab(lre[tg], lim[tg], step, bre[tg], bim[tg], ar, ai, br, bi);
        float xr = ar, xi = ai;                         // Abar^LC (LC=32: 5 squarings)
#pragma unroll
        for (int q = 0; q < 5; ++q) { float tt = xr * xr - xi * xi; xi = 2.f * xr * xi; xr = tt; }
        int dst = (lay * NST + n) * HD + ch;
        cA[dst]  = make_float2(ar, ai);
        cB[dst]  = make_float2(br, bi);
        cC[dst]  = make_float2(2.f * cre[tg], 2.f * cim[tg]);
        cAp[dst] = make_float2(xr, xi);
    }
#pragma unroll
    for (int it = 0; it < 2; ++it) {
        int i = (it * NTH + tg) * 8;                    // covers 4*HH floats
        float4 a = *(const float4*)(ow + i);
        float4 b = *(const float4*)(ow + i + 4);
        bf16x8 o;
        o[0]=(bf16)a.x; o[1]=(bf16)a.y; o[2]=(bf16)a.z; o[3]=(bf16)a.w;
        o[4]=(bf16)b.x; o[5]=(bf16)b.y; o[6]=(bf16)b.z; o[7]=(bf16)b.w;
        *(bf16x8*)(wb + i) = o;
        a = *(const float4*)(o2w + i);
        b = *(const float4*)(o2w + i + 4);
        o[0]=(bf16)a.x; o[1]=(bf16)a.y; o[2]=(bf16)a.z; o[3]=(bf16)a.w;
        o[4]=(bf16)b.x; o[5]=(bf16)b.y; o[6]=(bf16)b.z; o[7]=(bf16)b.w;
        *(bf16x8*)(wb + 4 * HH + i) = o;
    }
#pragma unroll
    for (int it = 0; it < 16; ++it) {
        int i = it * NTH + tg;
        int t = i >> 9, c = i & 511;
        float4 xv = *(const float4*)(x + t * 4);
        float4 wv4 = *(const float4*)(ew + c * 4);
        float acc = eb[c];
        acc = fmaf(xv.x, wv4.x, acc); acc = fmaf(xv.y, wv4.y, acc);
        acc = fmaf(xv.z, wv4.z, acc); acc = fmaf(xv.w, wv4.w, acc);
        h[i] = acc;
    }
    grid.sync();

    for (int lay = 0; lay < 4; ++lay) {
        // ================= A: LayerNorm stats (one wave per row, 2 rows) ==========
#pragma unroll
        for (int r = 0; r < 2; ++r) {
            int row = bid * 8 + r * 4 + wv;
            const float* hp = h + row * HD + lane * 8;
            float v[8];
            *(float4*)(v)     = *(const float4*)(hp);
            *(float4*)(v + 4) = *(const float4*)(hp + 4);
            float s = 0.f;
#pragma unroll
            for (int e = 0; e < 8; ++e) s += v[e];
            s = wave_reduce_add(s);
            float m = s * (1.f / HD);
            float q = 0.f;
#pragma unroll
            for (int e = 0; e < 8; ++e) { float d = v[e] - m; q += d * d; }
            q = wave_reduce_add(q);
            float rstd = rsqrtf(q * (1.f / HD) + 1e-5f);
            if (lane == 0) stats[row] = make_float2(m, rstd);
        }
        grid.sync();

        const int bx = bid & 31, byy = bid >> 5;        // 32 ch-groups x 8 t-groups
        const int t0 = byy * 256;                       // 256 rows per block
        const int chl = lane & 15, ch = bx * 16 + chl, sub = lane >> 4;
        const int cbase = (lay * NST + sub * 8) * HD + ch;

        // ================= B: P1 local chunk scans (tile staged, reused in E) =====
        {
            const float* ub = h + (size_t)t0 * HD + bx * 16;
#pragma unroll
            for (int rr = 0; rr < 16; ++rr) {
                int idx = rr * 256 + tid;
                tile[idx] = ub[(idx >> 4) * HD + (idx & 15)];
            }
            sst[tid] = stats[t0 + tid];
            if (tid < 16) {
                snw[tid] = nw[lay * HD + bx * 16 + tid];
                snb[tid] = nb[lay * HD + bx * 16 + tid];
            }
            float aR[8], aI[8], bR[8], bI[8];
#pragma unroll
            for (int j = 0; j < 8; ++j) {
                float2 t = cA[cbase + j * HD]; aR[j] = t.x; aI[j] = t.y;
                t = cB[cbase + j * HD];        bR[j] = t.x; bI[j] = t.y;
            }
            __syncthreads();
            float wch = snw[chl], bch = snb[chl];
#pragma unroll
            for (int k = 0; k < 2; ++k) {               // wave handles 2 chunks
                int chunk = byy * 8 + wv * 2 + k;
                float sr[8], si[8];
#pragma unroll
                for (int j = 0; j < 8; ++j) { sr[j] = 0.f; si[j] = 0.f; }
#pragma unroll 4
                for (int t = 0; t < LC; ++t) {
                    int row = wv * 64 + k * 32 + t;
                    float2 st = sst[row];
                    float uu = (tile[row * 16 + chl] - st.x) * st.y * wch + bch;
#pragma unroll
                    for (int j = 0; j < 8; ++j) {
                        float nr = fmaf(aR[j], sr[j], fmaf(-aI[j], si[j], bR[j] * uu));
                        float ni = fmaf(aI[j], sr[j], fmaf( aR[j], si[j], bI[j] * uu));
                        sr[j] = nr; si[j] = ni;
                    }
                }
                float2* fp = f + ((size_t)chunk * NST + sub * 8) * HD + ch;
#pragma unroll
                for (int j = 0; j < 8; ++j) fp[j * HD] = make_float2(sr[j], si[j]);
            }
        }
        grid.sync();

        // ================= C: p2a in-super scan (in place) =================
#pragma unroll
        for (int rep = 0; rep < 2; ++rep) {
            int ii = rep * NTH + tg;
            int cch = ii & 511, ns = ii >> 9;
            int n = ns & 31, sup = ns >> 5;
            float2 ap = cAp[(lay * NST + n) * HD + cch];
            float2* fp = f + ((size_t)(sup * SUP) * NST + n) * HD + cch;
            float sr = 0.f, si = 0.f;
#pragma unroll
            for (int j = 0; j < SUP; ++j) {
                float2 v = fp[(size_t)j * NST * HD];
                float nr = fmaf(ap.x, sr, fmaf(-ap.y, si, v.x));
                float ni = fmaf(ap.y, sr, fmaf( ap.x, si, v.y));
                sr = nr; si = ni;
                fp[(size_t)j * NST * HD] = make_float2(sr, si);
            }
        }
        grid.sync();

        // ================= D: cross-super fix -> f2 =================
#pragma unroll
        for (int rep = 0; rep < 2; ++rep) {
            int ii = rep * NTH + tg;
            int cch = ii & 511, ns = ii >> 9;
            int n = ns & 31, sup = ns >> 5;
            float2 ap = cAp[(lay * NST + n) * HD + cch];
            float a8r = ap.x, a8i = ap.y;               // ap^SUP (3 squarings)
#pragma unroll
            for (int q = 0; q < 3; ++q) { float tt = a8r * a8r - a8i * a8i; a8i = 2.f * a8r * a8i; a8r = tt; }
            float Sr = 0.f, Si = 0.f;
            for (int k = 0; k < sup; ++k) {             // carry from previous supers
                float2 F = f[((size_t)(k * SUP + SUP - 1) * NST + n) * HD + cch];
                float nr = fmaf(a8r, Sr, fmaf(-a8i, Si, F.x));
                float ni = fmaf(a8i, Sr, fmaf( a8r, Si, F.y));
                Sr = nr; Si = ni;
            }
            float wr = ap.x, wi = ap.y;                 // ap^(j+1)
            size_t base = ((size_t)(sup * SUP) * NST + n) * HD + cch;
#pragma unroll
            for (int j = 0; j < SUP; ++j) {
                float2 v = f[base + (size_t)j * NST * HD];
                v.x += wr * Sr - wi * Si;
                v.y += wr * Si + wi * Sr;
                f2[base + (size_t)j * NST * HD] = v;
                float nwr = wr * ap.x - wi * ap.y;
                float nwi = wr * ap.y + wi * ap.x;
                wr = nwr; wi = nwi;
            }
        }
        grid.sync();

        // ================= E: P3 replay + gelu emit (reuses B's LDS tile) =========
        {
            float aR[8], aI[8], bR[8], bI[8], cR[8], cI[8];
#pragma unroll
            for (int j = 0; j < 8; ++j) {
                float2 t = cA[cbase + j * HD]; aR[j] = t.x; aI[j] = t.y;
                t = cB[cbase + j * HD];        bR[j] = t.x; bI[j] = t.y;
                t = cC[cbase + j * HD];        cR[j] = t.x; cI[j] = t.y;
            }
            float dch = dd[lay * HD + ch];
            float wch = snw[chl], bch = snb[chl];
            int chunk0 = byy * 8 + wv * 2;              // first of the wave's 2 chunks
            float sr[8], si[8];
            if (chunk0 > 0) {
                const float2* ip = f2 + ((size_t)(chunk0 - 1) * NST + sub * 8) * HD + ch;
#pragma unroll
                for (int j = 0; j < 8; ++j) { float2 v = ip[j * HD]; sr[j] = v.x; si[j] = v.y; }
            } else {
#pragma unroll
                for (int j = 0; j < 8; ++j) { sr[j] = 0.f; si[j] = 0.f; }
            }
            bf16* gp = g + (size_t)t0 * HD + ch;
#pragma unroll 4
            for (int t = 0; t < 2 * LC; ++t) {          // 2 chunks, state continues
                int row = wv * 64 + t;
                float2 st = sst[row];
                float uu = (tile[row * 16 + chl] - st.x) * st.y * wch + bch;
                float p = 0.f;
#pragma unroll
                for (int j = 0; j < 8; ++j) {
                    float nr = fmaf(aR[j], sr[j], fmaf(-aI[j], si[j], bR[j] * uu));
                    float ni = fmaf(aI[j], sr[j], fmaf( aR[j], si[j], bI[j] * uu));
                    sr[j] = nr; si[j] = ni;
                    p = fmaf(cR[j], nr, fmaf(-cI[j], ni, p));
                }
                p += __shfl_xor(p, 16);
                p += __shfl_xor(p, 32);
                float y = fmaf(dch, uu, p);
                if (sub == 0) gp[(size_t)row * HD] = (bf16)gelu_tanh(y);
            }
        }
        grid.sync();

        // ================= F: fused gated dual-matmul + residual =================
        {
            const bf16* W1 = wb + lay * HH;
            const bf16* W2 = wb + 4 * HH + lay * HH;
            const float* bias1 = ob + lay * HD;
            const float* bias2 = o2b + lay * HD;
            const int wm = wv >> 1, wn = wv & 1;
            const int mBase = (bid >> 3) * 64 + wm * 32;
            const int nBase = (bid & 7) * 64 + wn * 32;
            const int lrow = lane & 15, quad = lane >> 4;
            floatx4 acc1[2][2] = {{{0.f,0.f,0.f,0.f},{0.f,0.f,0.f,0.f}},{{0.f,0.f,0.f,0.f},{0.f,0.f,0.f,0.f}}};
            floatx4 acc2[2][2] = {{{0.f,0.f,0.f,0.f},{0.f,0.f,0.f,0.f}},{{0.f,0.f,0.f,0.f},{0.f,0.f,0.f,0.f}}};
            for (int k0 = 0; k0 < HD; k0 += 32) {
                int kk = k0 + quad * 8;
                bf16x8 a0 = *(const bf16x8*)(g + (mBase + lrow) * HD + kk);
                bf16x8 a1 = *(const bf16x8*)(g + (mBase + 16 + lrow) * HD + kk);
                bf16x8 p0 = *(const bf16x8*)(W1 + (nBase + lrow) * HD + kk);
                bf16x8 p1 = *(const bf16x8*)(W1 + (nBase + 16 + lrow) * HD + kk);
                bf16x8 q0 = *(const bf16x8*)(W2 + (nBase + lrow) * HD + kk);
                bf16x8 q1 = *(const bf16x8*)(W2 + (nBase + 16 + lrow) * HD + kk);
                acc1[0][0] = __builtin_amdgcn_mfma_f32_16x16x32_bf16(a0, p0, acc1[0][0], 0, 0, 0);
                acc1[0][1] = __builtin_amdgcn_mfma_f32_16x16x32_bf16(a0, p1, acc1[0][1], 0, 0, 0);
                acc1[1][0] = __builtin_amdgcn_mfma_f32_16x16x32_bf16(a1, p0, acc1[1][0], 0, 0, 0);
                acc1[1][1] = __builtin_amdgcn_mfma_f32_16x16x32_bf16(a1, p1, acc1[1][1], 0, 0, 0);
                acc2[0][0] = __builtin_amdgcn_mfma_f32_16x16x32_bf16(a0, q0, acc2[0][0], 0, 0, 0);
                acc2[0][1] = __builtin_amdgcn_mfma_f32_16x16x32_bf16(a0, q1, acc2[0][1], 0, 0, 0);
                acc2[1][0] = __builtin_amdgcn_mfma_f32_16x16x32_bf16(a1, q0, acc2[1][0], 0, 0, 0);
                acc2[1][1] = __builtin_amdgcn_mfma_f32_16x16x32_bf16(a1, q1, acc2[1][1], 0, 0, 0);
            }
#pragma unroll
            for (int fm = 0; fm < 2; ++fm)
#pragma unroll
                for (int fn = 0; fn < 2; ++fn) {
                    int j = nBase + fn * 16 + lrow;
                    float bb1 = bias1[j], bb2 = bias2[j];
#pragma unroll
                    for (int r = 0; r < 4; ++r) {
                        int t = mBase + fm * 16 + quad * 4 + r;
                        float z1 = acc1[fm][fn][r] + bb1;
                        float z2 = acc2[fm][fn][r] + bb2;
                        h[t * HD + j] += z1 / (1.f + __expf(-z2));
                    }
                }
        }
        grid.sync();
    }

    // ================= decoder =================
#pragma unroll
    for (int r = 0; r < 2; ++r) {
        int row = bid * 8 + r * 4 + wv;
        const float* hp = h + row * HD + lane * 8;
        float v[8];
        *(float4*)(v)     = *(const float4*)(hp);
        *(float4*)(v + 4) = *(const float4*)(hp + 4);
#pragma unroll
        for (int j = 0; j < 3; ++j) {
            const float* wp = dw + j * HD + lane * 8;
            float w8[8];
            *(float4*)(w8)     = *(const float4*)(wp);
            *(float4*)(w8 + 4) = *(const float4*)(wp + 4);
            float s = 0.f;
#pragma unroll
            for (int e = 0; e < 8; ++e) s = fmaf(v[e], w8[e], s);
            s = wave_reduce_add(s);
            if (lane == 0) out[row * 3 + j] = s + db[j];
        }
    }
}

// ==========================================================================
// Fallback path (round-5 multi-kernel, known-good) — used only if the
// cooperative launch is rejected by the runtime.
// ==========================================================================
__global__ __launch_bounds__(256) void prep_kernel(
    const float* __restrict__ lre, const float* __restrict__ lim,
    const float* __restrict__ bre, const float* __restrict__ bim,
    const float* __restrict__ cre, const float* __restrict__ cim,
    const float* __restrict__ ls,
    float2* __restrict__ cA, float2* __restrict__ cB,
    float2* __restrict__ cC, float2* __restrict__ cAp) {
    int tid = blockIdx.x * 256 + threadIdx.x;
    int lay = tid >> 14, rem = tid & 16383;
    int ch = rem >> 5, n = rem & 31;
    float step = __expf(ls[lay * HD + ch]);
    float ar, ai, br, bi;
    make_ab(lre[tid], lim[tid], step, bre[tid], bim[tid], ar, ai, br, bi);
    float xr = ar, xi = ai;
#pragma unroll
    for (int q = 0; q < 5; ++q) { float tt = xr * xr - xi * xi; xi = 2.f * xr * xi; xr = tt; }
    int dst = (lay * NST + n) * HD + ch;
    cA[dst]  = make_float2(ar, ai);
    cB[dst]  = make_float2(br, bi);
    cC[dst]  = make_float2(2.f * cre[tid], 2.f * cim[tid]);
    cAp[dst] = make_float2(xr, xi);
}

__global__ __launch_bounds__(256) void cvt_kernel(
    const float* __restrict__ ow, const float* __restrict__ o2w,
    bf16* __restrict__ wb) {
    const float* src = blockIdx.y ? o2w : ow;
    bf16* dst = wb + blockIdx.y * (4 * HH);
    int i = (blockIdx.x * 256 + threadIdx.x) * 8;
    float4 a = *(const float4*)(src + i);
    float4 b = *(const float4*)(src + i + 4);
    bf16x8 o;
    o[0] = (bf16)a.x; o[1] = (bf16)a.y; o[2] = (bf16)a.z; o[3] = (bf16)a.w;
    o[4] = (bf16)b.x; o[5] = (bf16)b.y; o[6] = (bf16)b.z; o[7] = (bf16)b.w;
    *(bf16x8*)(dst + i) = o;
}

__global__ __launch_bounds__(256) void enc_kernel(
    const float* __restrict__ x, const float* __restrict__ w,
    const float* __restrict__ b, float* __restrict__ h) {
    int idx = blockIdx.x * 256 + threadIdx.x;
    int t = idx >> 9, i = idx & (HD - 1);
    float acc = b[i];
    float4 xv = *(const float4*)(x + t * 4);
    float4 wv = *(const float4*)(w + i * 4);
    acc = fmaf(xv.x, wv.x, acc);
    acc = fmaf(xv.y, wv.y, acc);
    acc = fmaf(xv.z, wv.z, acc);
    acc = fmaf(xv.w, wv.w, acc);
    h[idx] = acc;
}

__global__ __launch_bounds__(256) void ln_kernel(
    const float* __restrict__ h, float* __restrict__ hn,
    const float* __restrict__ w, const float* __restrict__ b) {
    int wv = threadIdx.x >> 6, lane = threadIdx.x & 63;
    int row = blockIdx.x * 4 + wv;
    const float* hp = h + row * HD + lane * 8;
    float v[8];
    *(float4*)(v)     = *(const float4*)(hp);
    *(float4*)(v + 4) = *(const float4*)(hp + 4);
    float s = 0.f;
#pragma unroll
    for (int e = 0; e < 8; ++e) s += v[e];
    s = wave_reduce_add(s);
    float m = s * (1.f / HD);
    float q = 0.f;
#pragma unroll
    for (int e = 0; e < 8; ++e) { float d = v[e] - m; q += d * d; }
    q = wave_reduce_add(q);
    float rstd = rsqrtf(q * (1.f / HD) + 1e-5f);
    float w8[8], b8[8];
    *(float4*)(w8)     = *(const float4*)(w + lane * 8);
    *(float4*)(w8 + 4) = *(const float4*)(w + lane * 8 + 4);
    *(float4*)(b8)     = *(const float4*)(b + lane * 8);
    *(float4*)(b8 + 4) = *(const float4*)(b + lane * 8 + 4);
    float o[8];
#pragma unroll
    for (int e = 0; e < 8; ++e)
        o[e] = (v[e] - m) * rstd * w8[e] + b8[e];
    float* op = hn + row * HD + lane * 8;
    *(float4*)op       = *(float4*)o;
    *(float4*)(op + 4) = *(float4*)(o + 4);
}

__global__ __launch_bounds__(256, 2) void p1_kernel(
    const float* __restrict__ u,
    const float2* __restrict__ cA, const float2* __restrict__ cB,
    float2* __restrict__ f, int lay) {
    __shared__ float tile[4 * LC * 16];
    int tid = threadIdx.x;
    int lane = tid & 63, w = tid >> 6;
    int chl = lane & 15;
    int ch = blockIdx.x * 16 + chl;
    int sub = lane >> 4;
    int chunk = blockIdx.y * 4 + w;
    int t0 = blockIdx.y * 4 * LC;
    const float* ub = u + (size_t)t0 * HD + blockIdx.x * 16;
#pragma unroll
    for (int r = 0; r < 8; ++r) {
        int idx = r * 256 + tid;
        tile[idx] = ub[(idx >> 4) * HD + (idx & 15)];
    }
    int cbase = (lay * NST + sub * 8) * HD + ch;
    float aR[8], aI[8], bR[8], bI[8];
#pragma unroll
    for (int j = 0; j < 8; ++j) {
        float2 t = cA[cbase + j * HD]; aR[j] = t.x; aI[j] = t.y;
        t = cB[cbase + j * HD];        bR[j] = t.x; bI[j] = t.y;
    }
    float sr[8], si[8];
#pragma unroll
    for (int j = 0; j < 8; ++j) { sr[j] = 0.f; si[j] = 0.f; }
    __syncthreads();
    const float* tp = tile + (w * LC) * 16 + chl;
#pragma unroll 4
    for (int t = 0; t < LC; ++t) {
        float uu = tp[t * 16];
#pragma unroll
        for (int j = 0; j < 8; ++j) {
            float nr = fmaf(aR[j], sr[j], fmaf(-aI[j], si[j], bR[j] * uu));
            float ni = fmaf(aI[j], sr[j], fmaf( aR[j], si[j], bI[j] * uu));
            sr[j] = nr; si[j] = ni;
        }
    }
    float2* fp = f + (chunk * NST + sub * 8) * HD + ch;
#pragma unroll
    for (int j = 0; j < 8; ++j) fp[j * HD] = make_float2(sr[j], si[j]);
}

__global__ __launch_bounds__(256) void p2a_kernel(
    float2* __restrict__ f, const float2* __restrict__ cAp, int lay) {
    int tg = blockIdx.x * 256 + threadIdx.x;
    int ch = tg & 511;
    int ns = tg >> 9;
    int n = ns & 31, sup = ns >> 5;
    float2 ap = cAp[(lay * NST + n) * HD + ch];
    float2* fp = f + ((sup * SUP) * NST + n) * HD + ch;
    float sr = 0.f, si = 0.f;
#pragma unroll
    for (int j = 0; j < SUP; ++j) {
        float2 v = fp[(size_t)j * NST * HD];
        float nr = fmaf(ap.x, sr, fmaf(-ap.y, si, v.x));
        float ni = fmaf(ap.y, sr, fmaf( ap.x, si, v.y));
        sr = nr; si = ni;
        fp[(size_t)j * NST * HD] = make_float2(sr, si);
    }
}

__global__ __launch_bounds__(256) void p2b_kernel(
    float2* __restrict__ f, const float2* __restrict__ cAp, int lay) {
    int tg = blockIdx.x * 256 + threadIdx.x;
    int ch = tg & 511, n = tg >> 9;
    float2 ap = cAp[(lay * NST + n) * HD + ch];
    float xr = ap.x, xi = ap.y;
#pragma unroll
    for (int q = 0; q < 3; ++q) { float tt = xr * xr - xi * xi; xi = 2.f * xr * xi; xr = tt; }
    float2* fp = f + ((SUP - 1) * NST + n) * HD + ch;
    const size_t stride = (size_t)SUP * NST * HD;
    float sr = 0.f, si = 0.f;
#pragma unroll
    for (int k = 0; k < NSUP; ++k) {
        float2 v = fp[k * stride];
        float nr = fmaf(xr, sr, fmaf(-xi, si, v.x));
        float ni = fmaf(xi, sr, fmaf( xr, si, v.y));
        sr = nr; si = ni;
        fp[k * stride] = make_float2(sr, si);
    }
}

__global__ __launch_bounds__(256) void p2c_kernel(
    float2* __restrict__ f, const float2* __restrict__ cAp, int lay) {
    int tg = blockIdx.x * 256 + threadIdx.x;
    int ch = tg & 511;
    int ns = tg >> 9;
    int n = ns & 31, sup = ns >> 5;
    if (sup == 0) return;
    float2 ap = cAp[(lay * NST + n) * HD + ch];
    float2 S = f[((sup * SUP - 1) * NST + n) * HD + ch];
    float2* fp = f + ((sup * SUP) * NST + n) * HD + ch;
    float wr = ap.x, wi = ap.y;
#pragma unroll
    for (int j = 0; j < SUP - 1; ++j) {
        float2 v = fp[(size_t)j * NST * HD];
        v.x += wr * S.x - wi * S.y;
        v.y += wr * S.y + wi * S.x;
        fp[(size_t)j * NST * HD] = v;
        float nwr = wr * ap.x - wi * ap.y;
        float nwi = wr * ap.y + wi * ap.x;
        wr = nwr; wi = nwi;
    }
}

__global__ __launch_bounds__(256, 2) void p3_kernel(
    const float* __restrict__ u, const float2* __restrict__ f,
    const float2* __restrict__ cA, const float2* __restrict__ cB,
    const float2* __restrict__ cC, const float* __restrict__ d_p,
    bf16* __restrict__ g, int lay) {
    __shared__ float tile[4 * LC * 16];
    int tid = threadIdx.x;
    int lane = tid & 63, w = tid >> 6;
    int chl = lane & 15;
    int ch = blockIdx.x * 16 + chl;
    int sub = lane >> 4;
    int chunk = blockIdx.y * 4 + w;
    int t0 = blockIdx.y * 4 * LC;
    const float* ub = u + (size_t)t0 * HD + blockIdx.x * 16;
#pragma unroll
    for (int r = 0; r < 8; ++r) {
        int idx = r * 256 + tid;
        tile[idx] = ub[(idx >> 4) * HD + (idx & 15)];
    }
    int cbase = (lay * NST + sub * 8) * HD + ch;
    float aR[8], aI[8], bR[8], bI[8], cR[8], cI[8];
#pragma unroll
    for (int j = 0; j < 8; ++j) {
        float2 t = cA[cbase + j * HD]; aR[j] = t.x; aI[j] = t.y;
        t = cB[cbase + j * HD];        bR[j] = t.x; bI[j] = t.y;
        t = cC[cbase + j * HD];        cR[j] = t.x; cI[j] = t.y;
    }
    float dch = d_p[lay * HD + ch];
    float sr[8], si[8];
    if (chunk > 0) {
        const float2* ip = f + ((chunk - 1) * NST + sub * 8) * HD + ch;
#pragma unroll
        for (int j = 0; j < 8; ++j) { float2 v = ip[j * HD]; sr[j] = v.x; si[j] = v.y; }
    } else {
#pragma unroll
        for (int j = 0; j < 8; ++j) { sr[j] = 0.f; si[j] = 0.f; }
    }
    __syncthreads();
    const float* tp = tile + (w * LC) * 16 + chl;
    bf16* gp = g + (size_t)chunk * LC * HD + ch;
#pragma unroll 4
    for (int t = 0; t < LC; ++t) {
        float uu = tp[t * 16];
        float p = 0.f;
#pragma unroll
        for (int j = 0; j < 8; ++j) {
            float nr = fmaf(aR[j], sr[j], fmaf(-aI[j], si[j], bR[j] * uu));
            float ni = fmaf(aI[j], sr[j], fmaf( aR[j], si[j], bI[j] * uu));
            sr[j] = nr; si[j] = ni;
            p = fmaf(cR[j], nr, fmaf(-cI[j], ni, p));
        }
        p += __shfl_xor(p, 16);
        p += __shfl_xor(p, 32);
        float y = fmaf(dch, uu, p);
        if (sub == 0) gp[t * HD] = (bf16)gelu_tanh(y);
    }
}

__global__ __launch_bounds__(256) void mm_kernel(
    const bf16* __restrict__ A,
    const bf16* __restrict__ W1,
    const bf16* __restrict__ W2,
    const float* __restrict__ bias1, const float* __restrict__ bias2,
    float* __restrict__ Hio) {
    const int w = threadIdx.x >> 6, lane = threadIdx.x & 63;
    const int wm = w >> 1, wn = w & 1;
    const int mBase = blockIdx.y * 64 + wm * 32;
    const int nBase = blockIdx.x * 64 + wn * 32;
    const int lrow = lane & 15, quad = lane >> 4;

    floatx4 acc1[2][2] = {{{0.f,0.f,0.f,0.f},{0.f,0.f,0.f,0.f}},{{0.f,0.f,0.f,0.f},{0.f,0.f,0.f,0.f}}};
    floatx4 acc2[2][2] = {{{0.f,0.f,0.f,0.f},{0.f,0.f,0.f,0.f}},{{0.f,0.f,0.f,0.f},{0.f,0.f,0.f,0.f}}};

    for (int k0 = 0; k0 < HD; k0 += 32) {
        int kk = k0 + quad * 8;
        bf16x8 a0 = *(const bf16x8*)(A + (mBase + lrow) * HD + kk);
        bf16x8 a1 = *(const bf16x8*)(A + (mBase + 16 + lrow) * HD + kk);
        bf16x8 p0 = *(const bf16x8*)(W1 + (nBase + lrow) * HD + kk);
        bf16x8 p1 = *(const bf16x8*)(W1 + (nBase + 16 + lrow) * HD + kk);
        bf16x8 q0 = *(const bf16x8*)(W2 + (nBase + lrow) * HD + kk);
        bf16x8 q1 = *(const bf16x8*)(W2 + (nBase + 16 + lrow) * HD + kk);
        acc1[0][0] = __builtin_amdgcn_mfma_f32_16x16x32_bf16(a0, p0, acc1[0][0], 0, 0, 0);
        acc1[0][1] = __builtin_amdgcn_mfma_f32_16x16x32_bf16(a0, p1, acc1[0][1], 0, 0, 0);
        acc1[1][0] = __builtin_amdgcn_mfma_f32_16x16x32_bf16(a1, p0, acc1[1][0], 0, 0, 0);
        acc1[1][1] = __builtin_amdgcn_mfma_f32_16x16x32_bf16(a1, p1, acc1[1][1], 0, 0, 0);
        acc2[0][0] = __builtin_amdgcn_mfma_f32_16x16x32_bf16(a0, q0, acc2[0][0], 0, 0, 0);
        acc2[0][1] = __builtin_amdgcn_mfma_f32_16x16x32_bf16(a0, q1, acc2[0][1], 0, 0, 0);
        acc2[1][0] = __builtin_amdgcn_mfma_f32_16x16x32_bf16(a1, q0, acc2[1][0], 0, 0, 0);
        acc2[1][1] = __builtin_amdgcn_mfma_f32_16x16x32_bf16(a1, q1, acc2[1][1], 0, 0, 0);
    }

#pragma unroll
    for (int fm = 0; fm < 2; ++fm)
#pragma unroll
        for (int fn = 0; fn < 2; ++fn) {
            int j = nBase + fn * 16 + lrow;
            float bb1 = bias1[j], bb2 = bias2[j];
#pragma unroll
            for (int r = 0; r < 4; ++r) {
                int t = mBase + fm * 16 + quad * 4 + r;
                float z1 = acc1[fm][fn][r] + bb1;
                float z2 = acc2[fm][fn][r] + bb2;
                Hio[t * HD + j] += z1 / (1.f + __expf(-z2));
            }
        }
}

__global__ __launch_bounds__(192) void dec_kernel(
    const float* __restrict__ h, const float* __restrict__ w,
    const float* __restrict__ b, float* __restrict__ out) {
    int j = threadIdx.x >> 6, lane = threadIdx.x & 63;
    int t = blockIdx.x;
    const float* hp = h + t * HD + lane * 8;
    float v[8];
    *(float4*)(v)     = *(const float4*)(hp);
    *(float4*)(v + 4) = *(const float4*)(hp + 4);
    float w8[8];
    *(float4*)(w8)     = *(const float4*)(w + j * HD + lane * 8);
    *(float4*)(w8 + 4) = *(const float4*)(w + j * HD + lane * 8 + 4);
    float s = 0.f;
#pragma unroll
    for (int e = 0; e < 8; ++e) s = fmaf(v[e], w8[e], s);
    s = wave_reduce_add(s);
    if (lane == 0) out[t * 3 + j] = s + b[j];
}

extern "C" void kernel_launch(void* const* d_in, const int* in_sizes, int n_in,
                              void* d_out, int out_size, void* d_ws, size_t ws_size,
                              hipStream_t stream) {
    const float* x   = (const float*)d_in[0];
    const float* ew  = (const float*)d_in[1];
    const float* eb  = (const float*)d_in[2];
    const float* dw  = (const float*)d_in[3];
    const float* db  = (const float*)d_in[4];
    const float* nw  = (const float*)d_in[5];
    const float* nb  = (const float*)d_in[6];
    const float* lre = (const float*)d_in[7];
    const float* lim = (const float*)d_in[8];
    const float* bre = (const float*)d_in[9];
    const float* bim = (const float*)d_in[10];
    const float* cre = (const float*)d_in[11];
    const float* cim = (const float*)d_in[12];
    const float* dd  = (const float*)d_in[13];
    const float* ls  = (const float*)d_in[14];
    const float* ow  = (const float*)d_in[15];
    const float* ob  = (const float*)d_in[16];
    const float* o2w = (const float*)d_in[17];
    const float* o2b = (const float*)d_in[18];
    float* outp = (float*)d_out;
    char* wsp = (char*)d_ws;

    void* args[] = { &x, &ew, &eb, &dw, &db, &nw, &nb, &lre, &lim, &bre, &bim,
                     &cre, &cim, &dd, &ls, &ow, &ob, &o2w, &o2b, &outp, &wsp };
    hipError_t err = hipLaunchCooperativeKernel((void*)fused_kernel, dim3(GRID),
                                                dim3(BLK), args, 0, stream);
    if (err != hipSuccess) {
        (void)hipGetLastError();   // clear sticky error; run known-good fallback
        float*  h   = (float*)wsp;
        float*  hn  = (float*)(wsp + (4  << 20));
        float2* f   = (float2*)(wsp + (8  << 20));
        bf16*   g   = (bf16*)(wsp + (24 << 20));
        bf16*   wb  = (bf16*)(wsp + (26 << 20));
        float2* cA  = (float2*)(wsp + (30 << 20));
        float2* cB  = (float2*)(wsp + (30 << 20) + (512 << 10));
        float2* cC  = (float2*)(wsp + (31 << 20));
        float2* cAp = (float2*)(wsp + (31 << 20) + (512 << 10));

        prep_kernel<<<256, 256, 0, stream>>>(lre, lim, bre, bim, cre, cim, ls, cA, cB, cC, cAp);
        cvt_kernel<<<dim3(4 * HH / (256 * 8), 2), 256, 0, stream>>>(ow, o2w, wb);
        enc_kernel<<<LSEQ * HD / 256, 256, 0, stream>>>(x, ew, eb, h);
        for (int lay = 0; lay < 4; ++lay) {
            int oH = lay * HD;
            ln_kernel<<<LSEQ / 4, 256, 0, stream>>>(h, hn, nw + oH, nb + oH);
            p1_kernel<<<dim3(HD / 16, NCHK / 4), 256, 0, stream>>>(hn, cA, cB, f, lay);
            p2a_kernel<<<512, 256, 0, stream>>>(f, cAp, lay);
            p2b_kernel<<<64, 256, 0, stream>>>(f, cAp, lay);
            p2c_kernel<<<512, 256, 0, stream>>>(f, cAp, lay);
            p3_kernel<<<dim3(HD / 16, NCHK / 4), 256, 0, stream>>>(hn, f, cA, cB, cC, dd, g, lay);
            mm_kernel<<<dim3(HD / 64, LSEQ / 64), 256, 0, stream>>>(
                g, wb + lay * HH, wb + 4 * HH + lay * HH, ob + oH, o2b + oH, h);
        }
        dec_kernel<<<LSEQ, 192, 0, stream>>>(h, dw, db, outp);
    }
}

// Round 8
// 362.894 us; speedup vs baseline: 3.0349x; 3.0349x over previous
//
#include <hip/hip_runtime.h>
#include <hip/hip_bf16.h>
#include <math.h>

#define LSEQ 2048
#define HD   512
#define NST  32
#define LC   32
#define NCHK 64   /* LSEQ/LC */
#define HH   (HD * HD)

typedef __bf16 bf16;
typedef __bf16 bf16x8 __attribute__((ext_vector_type(8)));
typedef float  floatx4 __attribute__((ext_vector_type(4)));

__device__ __forceinline__ float wave_reduce_add(float v) {
#pragma unroll
    for (int m = 32; m; m >>= 1) v += __shfl_xor(v, m, 64);
    return v;
}

__device__ __forceinline__ float gelu_tanh(float x) {
    float z = 0.7978845608028654f * (x + 0.044715f * x * x * x);
    float e = __expf(2.f * z);
    float th = 1.f - 2.f / (e + 1.f);   // tanh(z), saturates cleanly at e=inf
    return 0.5f * x * (1.f + th);
}

__device__ __forceinline__ void make_ab(float lre, float lim, float step,
                                        float br0, float bi0,
                                        float& ar, float& ai, float& br, float& bi) {
    float s2 = 0.5f * step;
    float dr = 1.f - s2 * lre, di = -s2 * lim;      // 1 - (dt/2)Lam
    float inv = 1.f / (dr * dr + di * di);
    float blr = dr * inv, bli = -di * inv;          // BL = 1/(dr+i*di)
    float nr = 1.f + s2 * lre, ni = s2 * lim;       // 1 + (dt/2)Lam
    ar = blr * nr - bli * ni;
    ai = blr * ni + bli * nr;
    float tr = step * br0, ti = step * bi0;         // dt * B
    br = blr * tr - bli * ti;
    bi = blr * ti + bli * tr;
}

// ============ setup: prep coeffs (blocks 0..255) + weight cvt (256..767)
// ============        + encoder w/ layer-0 LN-stat atomics (768..4863)
__global__ __launch_bounds__(256) void setup_kernel(
    const float* __restrict__ x,   const float* __restrict__ ew,
    const float* __restrict__ eb,
    const float* __restrict__ lre, const float* __restrict__ lim,
    const float* __restrict__ bre, const float* __restrict__ bim,
    const float* __restrict__ cre, const float* __restrict__ cim,
    const float* __restrict__ ls,  const float* __restrict__ ow,
    const float* __restrict__ o2w,
    float* __restrict__ h, bf16* __restrict__ wb,
    float2* __restrict__ cA, float2* __restrict__ cB,
    float2* __restrict__ cC, float2* __restrict__ cAp,
    float* __restrict__ st0)
{
    int bid = blockIdx.x, tid = threadIdx.x;
    if (bid < 256) {
        int tg = bid * 256 + tid;                   // 65536 = 4*HD*NST
        int lay = tg >> 14, rem = tg & 16383;
        int ch = rem >> 5, n = rem & 31;
        float step = __expf(ls[lay * HD + ch]);
        float ar, ai, br, bi;
        make_ab(lre[tg], lim[tg], step, bre[tg], bim[tg], ar, ai, br, bi);
        float xr = ar, xi = ai;                     // Abar^LC (LC=32: 5 squarings)
#pragma unroll
        for (int q = 0; q < 5; ++q) { float tt = xr * xr - xi * xi; xi = 2.f * xr * xi; xr = tt; }
        int dst = (lay * NST + n) * HD + ch;
        cA[dst]  = make_float2(ar, ai);
        cB[dst]  = make_float2(br, bi);
        cC[dst]  = make_float2(2.f * cre[tg], 2.f * cim[tg]);
        cAp[dst] = make_float2(xr, xi);
    } else if (bid < 768) {
        int i = ((bid - 256) * 256 + tid) * 8;      // covers 4*HH floats
        float4 a = *(const float4*)(ow + i);
        float4 b = *(const float4*)(ow + i + 4);
        bf16x8 o;
        o[0]=(bf16)a.x; o[1]=(bf16)a.y; o[2]=(bf16)a.z; o[3]=(bf16)a.w;
        o[4]=(bf16)b.x; o[5]=(bf16)b.y; o[6]=(bf16)b.z; o[7]=(bf16)b.w;
        *(bf16x8*)(wb + i) = o;
        a = *(const float4*)(o2w + i);
        b = *(const float4*)(o2w + i + 4);
        o[0]=(bf16)a.x; o[1]=(bf16)a.y; o[2]=(bf16)a.z; o[3]=(bf16)a.w;
        o[4]=(bf16)b.x; o[5]=(bf16)b.y; o[6]=(bf16)b.z; o[7]=(bf16)b.w;
        *(bf16x8*)(wb + 4 * HH + i) = o;
    } else {
        int i = (bid - 768) * 256 + tid;            // 1048576 = L*HD
        int t = i >> 9, c = i & 511;
        float4 xv = *(const float4*)(x + t * 4);
        float4 wv = *(const float4*)(ew + c * 4);
        float acc = eb[c];
        acc = fmaf(xv.x, wv.x, acc); acc = fmaf(xv.y, wv.y, acc);
        acc = fmaf(xv.z, wv.z, acc); acc = fmaf(xv.w, wv.w, acc);
        h[i] = acc;
        float s1 = wave_reduce_add(acc);
        float s2 = wave_reduce_add(acc * acc);
        if ((tid & 63) == 0) {
            atomicAdd(&st0[t * 2],     s1);
            atomicAdd(&st0[t * 2 + 1], s2);
        }
    }
}

// ============ P1: chunk-local scans, LN applied on the fly from staged tile ====
__global__ __launch_bounds__(256, 2) void p1_kernel(
    const float* __restrict__ h, const float* __restrict__ st,
    const float2* __restrict__ cA, const float2* __restrict__ cB,
    const float* __restrict__ nw, const float* __restrict__ nb,
    float2* __restrict__ f, int lay) {
    __shared__ float  tile[4 * LC * 16];            // 8 KB: 128 rows x 16 ch
    __shared__ float2 sml[128];                     // (m, rstd) per row
    __shared__ float  snw[16], snb[16];
    int tid = threadIdx.x;
    int lane = tid & 63, w = tid >> 6;
    int chl = lane & 15;
    int ch = blockIdx.x * 16 + chl;
    int sub = lane >> 4;
    int chunk = blockIdx.y * 4 + w;
    int t0 = blockIdx.y * 4 * LC;
    const float* ub = h + (size_t)t0 * HD + blockIdx.x * 16;
#pragma unroll
    for (int r = 0; r < 8; ++r) {
        int idx = r * 256 + tid;
        tile[idx] = ub[(idx >> 4) * HD + (idx & 15)];
    }
    if (tid < 128) {
        float s1 = st[(t0 + tid) * 2], s2 = st[(t0 + tid) * 2 + 1];
        float m = s1 * (1.f / HD);
        float var = s2 * (1.f / HD) - m * m;
        sml[tid] = make_float2(m, rsqrtf(var + 1e-5f));
    }
    if (tid < 16) {
        snw[tid] = nw[lay * HD + blockIdx.x * 16 + tid];
        snb[tid] = nb[lay * HD + blockIdx.x * 16 + tid];
    }
    int cbase = (lay * NST + sub * 8) * HD + ch;
    float aR[8], aI[8], bR[8], bI[8];
#pragma unroll
    for (int j = 0; j < 8; ++j) {
        float2 t = cA[cbase + j * HD]; aR[j] = t.x; aI[j] = t.y;
        t = cB[cbase + j * HD];        bR[j] = t.x; bI[j] = t.y;
    }
    float sr[8], si[8];
#pragma unroll
    for (int j = 0; j < 8; ++j) { sr[j] = 0.f; si[j] = 0.f; }
    __syncthreads();
    float wch = snw[chl], bch = snb[chl];
#pragma unroll 4
    for (int t = 0; t < LC; ++t) {
        int row = w * LC + t;
        float2 ms = sml[row];
        float uu = (tile[row * 16 + chl] - ms.x) * ms.y * wch + bch;
#pragma unroll
        for (int j = 0; j < 8; ++j) {
            float nr = fmaf(aR[j], sr[j], fmaf(-aI[j], si[j], bR[j] * uu));
            float ni = fmaf(aI[j], sr[j], fmaf( aR[j], si[j], bI[j] * uu));
            sr[j] = nr; si[j] = ni;
        }
    }
    float2* fp = f + ((size_t)chunk * NST + sub * 8) * HD + ch;
#pragma unroll
    for (int j = 0; j < 8; ++j) fp[j * HD] = make_float2(sr[j], si[j]);
}

// ============ P2: wave-parallel affine scan over 64 chunk-finals (in place) ====
// lane = chunk; (v,w) <- (v + w*v_prev, w*w_prev), 6 Hillis-Steele steps
__global__ __launch_bounds__(256) void p2_kernel(
    float2* __restrict__ f, const float2* __restrict__ cAp, int lay) {
    int w = threadIdx.x >> 6, lane = threadIdx.x & 63;
    int chain = blockIdx.x * 4 + w;                 // 16384 = HD*NST
    int ch = chain & 511, n = chain >> 9;
    float2 ap = cAp[(lay * NST + n) * HD + ch];
    size_t idx = ((size_t)lane * NST + n) * HD + ch;
    float2 v = f[idx];
    float vr = v.x, vi = v.y, wr = ap.x, wi = ap.y;
#pragma unroll
    for (int d = 1; d < 64; d <<= 1) {
        float pvr = __shfl_up(vr, d, 64);
        float pvi = __shfl_up(vi, d, 64);
        float pwr = __shfl_up(wr, d, 64);
        float pwi = __shfl_up(wi, d, 64);
        if (lane >= d) {
            vr += wr * pvr - wi * pvi;
            vi += wr * pvi + wi * pvr;
            float nr = wr * pwr - wi * pwi;
            float ni = wr * pwi + wi * pwr;
            wr = nr; wi = ni;
        }
    }
    f[idx] = make_float2(vr, vi);
}

// ============ P3: replay with carried init, LN on the fly, emit gelu(y) bf16 ===
__global__ __launch_bounds__(256, 2) void p3_kernel(
    const float* __restrict__ h, const float* __restrict__ st,
    const float2* __restrict__ f,
    const float2* __restrict__ cA, const float2* __restrict__ cB,
    const float2* __restrict__ cC, const float* __restrict__ dd,
    const float* __restrict__ nw, const float* __restrict__ nb,
    bf16* __restrict__ g, int lay) {
    __shared__ float  tile[4 * LC * 16];
    __shared__ float2 sml[128];
    __shared__ float  snw[16], snb[16];
    int tid = threadIdx.x;
    int lane = tid & 63, w = tid >> 6;
    int chl = lane & 15;
    int ch = blockIdx.x * 16 + chl;
    int sub = lane >> 4;
    int chunk = blockIdx.y * 4 + w;
    int t0 = blockIdx.y * 4 * LC;
    const float* ub = h + (size_t)t0 * HD + blockIdx.x * 16;
#pragma unroll
    for (int r = 0; r < 8; ++r) {
        int idx = r * 256 + tid;
        tile[idx] = ub[(idx >> 4) * HD + (idx & 15)];
    }
    if (tid < 128) {
        float s1 = st[(t0 + tid) * 2], s2 = st[(t0 + tid) * 2 + 1];
        float m = s1 * (1.f / HD);
        float var = s2 * (1.f / HD) - m * m;
        sml[tid] = make_float2(m, rsqrtf(var + 1e-5f));
    }
    if (tid < 16) {
        snw[tid] = nw[lay * HD + blockIdx.x * 16 + tid];
        snb[tid] = nb[lay * HD + blockIdx.x * 16 + tid];
    }
    int cbase = (lay * NST + sub * 8) * HD + ch;
    float aR[8], aI[8], bR[8], bI[8], cR[8], cI[8];
#pragma unroll
    for (int j = 0; j < 8; ++j) {
        float2 t = cA[cbase + j * HD]; aR[j] = t.x; aI[j] = t.y;
        t = cB[cbase + j * HD];        bR[j] = t.x; bI[j] = t.y;
        t = cC[cbase + j * HD];        cR[j] = t.x; cI[j] = t.y;
    }
    float dch = dd[lay * HD + ch];
    float sr[8], si[8];
    if (chunk > 0) {
        const float2* ip = f + ((size_t)(chunk - 1) * NST + sub * 8) * HD + ch;
#pragma unroll
        for (int j = 0; j < 8; ++j) { float2 v = ip[j * HD]; sr[j] = v.x; si[j] = v.y; }
    } else {
#pragma unroll
        for (int j = 0; j < 8; ++j) { sr[j] = 0.f; si[j] = 0.f; }
    }
    __syncthreads();
    float wch = snw[chl], bch = snb[chl];
    bf16* gp = g + (size_t)chunk * LC * HD + ch;
#pragma unroll 4
    for (int t = 0; t < LC; ++t) {
        int row = w * LC + t;
        float2 ms = sml[row];
        float uu = (tile[row * 16 + chl] - ms.x) * ms.y * wch + bch;
        float p = 0.f;
#pragma unroll
        for (int j = 0; j < 8; ++j) {
            float nr = fmaf(aR[j], sr[j], fmaf(-aI[j], si[j], bR[j] * uu));
            float ni = fmaf(aI[j], sr[j], fmaf( aR[j], si[j], bI[j] * uu));
            sr[j] = nr; si[j] = ni;
            p = fmaf(cR[j], nr, fmaf(-cI[j], ni, p));   // cC pre-scaled by 2
        }
        p += __shfl_xor(p, 16);
        p += __shfl_xor(p, 32);
        float y = fmaf(dch, uu, p);
        if (sub == 0) gp[t * HD] = (bf16)gelu_tanh(y);
    }
}

// ============ mm: gated dual-matmul + residual + NEXT layer's LN-stat atomics ==
__global__ __launch_bounds__(256) void mm_kernel(
    const bf16* __restrict__ A,
    const bf16* __restrict__ W1,
    const bf16* __restrict__ W2,
    const float* __restrict__ bias1, const float* __restrict__ bias2,
    float* __restrict__ Hio, float* __restrict__ stn) {
    const int w = threadIdx.x >> 6, lane = threadIdx.x & 63;
    const int wm = w >> 1, wn = w & 1;
    const int mBase = blockIdx.y * 64 + wm * 32;
    const int nBase = blockIdx.x * 64 + wn * 32;
    const int lrow = lane & 15, quad = lane >> 4;

    floatx4 acc1[2][2] = {{{0.f,0.f,0.f,0.f},{0.f,0.f,0.f,0.f}},{{0.f,0.f,0.f,0.f},{0.f,0.f,0.f,0.f}}};
    floatx4 acc2[2][2] = {{{0.f,0.f,0.f,0.f},{0.f,0.f,0.f,0.f}},{{0.f,0.f,0.f,0.f},{0.f,0.f,0.f,0.f}}};

    for (int k0 = 0; k0 < HD; k0 += 32) {
        int kk = k0 + quad * 8;
        bf16x8 a0 = *(const bf16x8*)(A + (mBase + lrow) * HD + kk);
        bf16x8 a1 = *(const bf16x8*)(A + (mBase + 16 + lrow) * HD + kk);
        bf16x8 p0 = *(const bf16x8*)(W1 + (nBase + lrow) * HD + kk);
        bf16x8 p1 = *(const bf16x8*)(W1 + (nBase + 16 + lrow) * HD + kk);
        bf16x8 q0 = *(const bf16x8*)(W2 + (nBase + lrow) * HD + kk);
        bf16x8 q1 = *(const bf16x8*)(W2 + (nBase + 16 + lrow) * HD + kk);
        acc1[0][0] = __builtin_amdgcn_mfma_f32_16x16x32_bf16(a0, p0, acc1[0][0], 0, 0, 0);
        acc1[0][1] = __builtin_amdgcn_mfma_f32_16x16x32_bf16(a0, p1, acc1[0][1], 0, 0, 0);
        acc1[1][0] = __builtin_amdgcn_mfma_f32_16x16x32_bf16(a1, p0, acc1[1][0], 0, 0, 0);
        acc1[1][1] = __builtin_amdgcn_mfma_f32_16x16x32_bf16(a1, p1, acc1[1][1], 0, 0, 0);
        acc2[0][0] = __builtin_amdgcn_mfma_f32_16x16x32_bf16(a0, q0, acc2[0][0], 0, 0, 0);
        acc2[0][1] = __builtin_amdgcn_mfma_f32_16x16x32_bf16(a0, q1, acc2[0][1], 0, 0, 0);
        acc2[1][0] = __builtin_amdgcn_mfma_f32_16x16x32_bf16(a1, q0, acc2[1][0], 0, 0, 0);
        acc2[1][1] = __builtin_amdgcn_mfma_f32_16x16x32_bf16(a1, q1, acc2[1][1], 0, 0, 0);
    }

    float hv[2][2][4];
#pragma unroll
    for (int fm = 0; fm < 2; ++fm)
#pragma unroll
        for (int fn = 0; fn < 2; ++fn) {
            int j = nBase + fn * 16 + lrow;
            float bb1 = bias1[j], bb2 = bias2[j];
#pragma unroll
            for (int r = 0; r < 4; ++r) {
                int t = mBase + fm * 16 + quad * 4 + r;
                float z1 = acc1[fm][fn][r] + bb1;
                float z2 = acc2[fm][fn][r] + bb2;
                float nv = Hio[t * HD + j] + z1 / (1.f + __expf(-z2));
                Hio[t * HD + j] = nv;
                hv[fm][fn][r] = nv;
            }
        }
    // accumulate next layer's LN stats (sum, sumsq per row)
#pragma unroll
    for (int fm = 0; fm < 2; ++fm)
#pragma unroll
        for (int r = 0; r < 4; ++r) {
            int t = mBase + fm * 16 + quad * 4 + r;
            float s1 = hv[fm][0][r] + hv[fm][1][r];
            float s2 = hv[fm][0][r] * hv[fm][0][r] + hv[fm][1][r] * hv[fm][1][r];
#pragma unroll
            for (int m = 1; m < 16; m <<= 1) {
                s1 += __shfl_xor(s1, m);
                s2 += __shfl_xor(s2, m);
            }
            if (lrow == 0) {
                atomicAdd(&stn[t * 2],     s1);
                atomicAdd(&stn[t * 2 + 1], s2);
            }
        }
}

// ============ decoder ============
__global__ __launch_bounds__(192) void dec_kernel(
    const float* __restrict__ h, const float* __restrict__ w,
    const float* __restrict__ b, float* __restrict__ out) {
    int j = threadIdx.x >> 6, lane = threadIdx.x & 63;
    int t = blockIdx.x;
    const float* hp = h + t * HD + lane * 8;
    float v[8];
    *(float4*)(v)     = *(const float4*)(hp);
    *(float4*)(v + 4) = *(const float4*)(hp + 4);
    float w8[8];
    *(float4*)(w8)     = *(const float4*)(w + j * HD + lane * 8);
    *(float4*)(w8 + 4) = *(const float4*)(w + j * HD + lane * 8 + 4);
    float s = 0.f;
#pragma unroll
    for (int e = 0; e < 8; ++e) s = fmaf(v[e], w8[e], s);
    s = wave_reduce_add(s);
    if (lane == 0) out[t * 3 + j] = s + b[j];
}

extern "C" void kernel_launch(void* const* d_in, const int* in_sizes, int n_in,
                              void* d_out, int out_size, void* d_ws, size_t ws_size,
                              hipStream_t stream) {
    const float* x   = (const float*)d_in[0];
    const float* ew  = (const float*)d_in[1];
    const float* eb  = (const float*)d_in[2];
    const float* dw  = (const float*)d_in[3];
    const float* db  = (const float*)d_in[4];
    const float* nw  = (const float*)d_in[5];
    const float* nb  = (const float*)d_in[6];
    const float* lre = (const float*)d_in[7];
    const float* lim = (const float*)d_in[8];
    const float* bre = (const float*)d_in[9];
    const float* bim = (const float*)d_in[10];
    const float* cre = (const float*)d_in[11];
    const float* cim = (const float*)d_in[12];
    const float* dd  = (const float*)d_in[13];
    const float* ls  = (const float*)d_in[14];
    const float* ow  = (const float*)d_in[15];
    const float* ob  = (const float*)d_in[16];
    const float* o2w = (const float*)d_in[17];
    const float* o2b = (const float*)d_in[18];
    char* ws = (char*)d_ws;

    float*  h     = (float*)ws;                           // 4 MB  [L][HD]
    float2* f     = (float2*)(ws + (4  << 20));           // 8 MB  [NCHK][NST][HD]
    bf16*   g     = (bf16*)(ws + (12 << 20));             // 2 MB  [L][HD] bf16
    bf16*   wb    = (bf16*)(ws + (14 << 20));             // 4 MB  bf16 weights
    float*  stats = (float*)(ws + (18 << 20));            // 5 slots x 2048 x 2 f32 = 80 KB
    float2* cA    = (float2*)(ws + (19 << 20));           // 4 x 512 KB
    float2* cB    = cA + 4 * NST * HD;
    float2* cC    = cB + 4 * NST * HD;
    float2* cAp   = cC + 4 * NST * HD;

    hipMemsetAsync(stats, 0, 5 * LSEQ * 2 * sizeof(float), stream);
    setup_kernel<<<4864, 256, 0, stream>>>(x, ew, eb, lre, lim, bre, bim,
                                           cre, cim, ls, ow, o2w,
                                           h, wb, cA, cB, cC, cAp, stats);
    for (int lay = 0; lay < 4; ++lay) {
        float* st  = stats + lay * LSEQ * 2;
        float* stn = stats + (lay + 1) * LSEQ * 2;
        p1_kernel<<<dim3(32, 16), 256, 0, stream>>>(h, st, cA, cB, nw, nb, f, lay);
        p2_kernel<<<4096, 256, 0, stream>>>(f, cAp, lay);
        p3_kernel<<<dim3(32, 16), 256, 0, stream>>>(h, st, f, cA, cB, cC, dd, nw, nb, g, lay);
        mm_kernel<<<dim3(8, 32), 256, 0, stream>>>(
            g, wb + lay * HH, wb + 4 * HH + lay * HH,
            ob + lay * HD, o2b + lay * HD, h, stn);
    }
    dec_kernel<<<LSEQ, 192, 0, stream>>>(h, dw, db, (float*)d_out);
}

// Round 9
// 339.027 us; speedup vs baseline: 3.2485x; 1.0704x over previous
//
#include <hip/hip_runtime.h>
#include <hip/hip_bf16.h>
#include <math.h>

#define LSEQ 2048
#define HD   512
#define NST  32
#define LC   32
#define NCHK 64   /* LSEQ/LC */
#define SUP  8    /* chunks per superchunk */
#define NSUP 8    /* NCHK/SUP */
#define HH   (HD * HD)

typedef __bf16 bf16;
typedef __bf16 bf16x8 __attribute__((ext_vector_type(8)));
typedef float  floatx4 __attribute__((ext_vector_type(4)));

__device__ __forceinline__ float wave_reduce_add(float v) {
#pragma unroll
    for (int m = 32; m; m >>= 1) v += __shfl_xor(v, m, 64);
    return v;
}

__device__ __forceinline__ float gelu_tanh(float x) {
    float z = 0.7978845608028654f * (x + 0.044715f * x * x * x);
    float e = __expf(2.f * z);
    float th = 1.f - 2.f / (e + 1.f);   // tanh(z), saturates cleanly at e=inf
    return 0.5f * x * (1.f + th);
}

__device__ __forceinline__ void make_ab(float lre, float lim, float step,
                                        float br0, float bi0,
                                        float& ar, float& ai, float& br, float& bi) {
    float s2 = 0.5f * step;
    float dr = 1.f - s2 * lre, di = -s2 * lim;      // 1 - (dt/2)Lam
    float inv = 1.f / (dr * dr + di * di);
    float blr = dr * inv, bli = -di * inv;          // BL = 1/(dr+i*di)
    float nr = 1.f + s2 * lre, ni = s2 * lim;       // 1 + (dt/2)Lam
    ar = blr * nr - bli * ni;
    ai = blr * ni + bli * nr;
    float tr = step * br0, ti = step * bi0;         // dt * B
    br = blr * tr - bli * ti;
    bi = blr * ti + bli * tr;
}

// ============ setup: prep coeffs (blocks 0..255) + weight cvt (256..767)
// ============        + encoder w/ layer-0 LN-stat atomics (768..4863)
__global__ __launch_bounds__(256) void setup_kernel(
    const float* __restrict__ x,   const float* __restrict__ ew,
    const float* __restrict__ eb,
    const float* __restrict__ lre, const float* __restrict__ lim,
    const float* __restrict__ bre, const float* __restrict__ bim,
    const float* __restrict__ cre, const float* __restrict__ cim,
    const float* __restrict__ ls,  const float* __restrict__ ow,
    const float* __restrict__ o2w,
    float* __restrict__ h, bf16* __restrict__ wb,
    float2* __restrict__ cA, float2* __restrict__ cB,
    float2* __restrict__ cC, float2* __restrict__ cAp,
    float* __restrict__ st0)
{
    int bid = blockIdx.x, tid = threadIdx.x;
    if (bid < 256) {
        int tg = bid * 256 + tid;                   // 65536 = 4*HD*NST
        int lay = tg >> 14, rem = tg & 16383;
        int ch = rem >> 5, n = rem & 31;
        float step = __expf(ls[lay * HD + ch]);
        float ar, ai, br, bi;
        make_ab(lre[tg], lim[tg], step, bre[tg], bim[tg], ar, ai, br, bi);
        float xr = ar, xi = ai;                     // Abar^LC (LC=32: 5 squarings)
#pragma unroll
        for (int q = 0; q < 5; ++q) { float tt = xr * xr - xi * xi; xi = 2.f * xr * xi; xr = tt; }
        int dst = (lay * NST + n) * HD + ch;
        cA[dst]  = make_float2(ar, ai);
        cB[dst]  = make_float2(br, bi);
        cC[dst]  = make_float2(2.f * cre[tg], 2.f * cim[tg]);
        cAp[dst] = make_float2(xr, xi);
    } else if (bid < 768) {
        int i = ((bid - 256) * 256 + tid) * 8;      // covers 4*HH floats
        float4 a = *(const float4*)(ow + i);
        float4 b = *(const float4*)(ow + i + 4);
        bf16x8 o;
        o[0]=(bf16)a.x; o[1]=(bf16)a.y; o[2]=(bf16)a.z; o[3]=(bf16)a.w;
        o[4]=(bf16)b.x; o[5]=(bf16)b.y; o[6]=(bf16)b.z; o[7]=(bf16)b.w;
        *(bf16x8*)(wb + i) = o;
        a = *(const float4*)(o2w + i);
        b = *(const float4*)(o2w + i + 4);
        o[0]=(bf16)a.x; o[1]=(bf16)a.y; o[2]=(bf16)a.z; o[3]=(bf16)a.w;
        o[4]=(bf16)b.x; o[5]=(bf16)b.y; o[6]=(bf16)b.z; o[7]=(bf16)b.w;
        *(bf16x8*)(wb + 4 * HH + i) = o;
    } else {
        int i = (bid - 768) * 256 + tid;            // 1048576 = L*HD
        int t = i >> 9, c = i & 511;
        float4 xv = *(const float4*)(x + t * 4);
        float4 wv = *(const float4*)(ew + c * 4);
        float acc = eb[c];
        acc = fmaf(xv.x, wv.x, acc); acc = fmaf(xv.y, wv.y, acc);
        acc = fmaf(xv.z, wv.z, acc); acc = fmaf(xv.w, wv.w, acc);
        h[i] = acc;
        float s1 = wave_reduce_add(acc);
        float s2 = wave_reduce_add(acc * acc);
        if ((tid & 63) == 0) {
            atomicAdd(&st0[t * 2],     s1);
            atomicAdd(&st0[t * 2 + 1], s2);
        }
    }
}

// ============ P1: chunk-local scans. 4 states/lane, 8 ch/wave, 1024 blocks ====
__global__ __launch_bounds__(256) void p1_kernel(
    const float* __restrict__ h, const float* __restrict__ st,
    const float2* __restrict__ cA, const float2* __restrict__ cB,
    const float* __restrict__ nw, const float* __restrict__ nb,
    float2* __restrict__ f, int lay) {
    __shared__ float  tile[4 * LC * 8];             // 4 KB: 128 rows x 8 ch
    __shared__ float2 sml[128];
    __shared__ float  snw[8], snb[8];
    int tid = threadIdx.x;
    int lane = tid & 63, w = tid >> 6;
    int chl = lane & 7;
    int ch = blockIdx.x * 8 + chl;
    int sub = lane >> 3;                            // 0..7, 4 states each
    int chunk = blockIdx.y * 4 + w;
    int t0 = blockIdx.y * 4 * LC;
    const float* ub = h + (size_t)t0 * HD + blockIdx.x * 8;
#pragma unroll
    for (int r = 0; r < 4; ++r) {
        int idx = r * 256 + tid;
        tile[idx] = ub[(idx >> 3) * HD + (idx & 7)];
    }
    if (tid < 128) {
        float s1 = st[(t0 + tid) * 2], s2 = st[(t0 + tid) * 2 + 1];
        float m = s1 * (1.f / HD);
        float var = s2 * (1.f / HD) - m * m;
        sml[tid] = make_float2(m, rsqrtf(var + 1e-5f));
    }
    if (tid < 8) {
        snw[tid] = nw[lay * HD + blockIdx.x * 8 + tid];
        snb[tid] = nb[lay * HD + blockIdx.x * 8 + tid];
    }
    int cbase = (lay * NST + sub * 4) * HD + ch;
    float aR[4], aI[4], bR[4], bI[4];
#pragma unroll
    for (int j = 0; j < 4; ++j) {
        float2 t = cA[cbase + j * HD]; aR[j] = t.x; aI[j] = t.y;
        t = cB[cbase + j * HD];        bR[j] = t.x; bI[j] = t.y;
    }
    float sr[4] = {0,0,0,0}, si[4] = {0,0,0,0};
    __syncthreads();
    float wch = snw[chl], bch = snb[chl];
#pragma unroll 4
    for (int t = 0; t < LC; ++t) {
        int row = w * LC + t;
        float2 ms = sml[row];
        float uu = (tile[row * 8 + chl] - ms.x) * ms.y * wch + bch;
#pragma unroll
        for (int j = 0; j < 4; ++j) {
            float nr = fmaf(aR[j], sr[j], fmaf(-aI[j], si[j], bR[j] * uu));
            float ni = fmaf(aI[j], sr[j], fmaf( aR[j], si[j], bI[j] * uu));
            sr[j] = nr; si[j] = ni;
        }
    }
    float2* fp = f + ((size_t)chunk * NST + sub * 4) * HD + ch;
#pragma unroll
    for (int j = 0; j < 4; ++j) fp[j * HD] = make_float2(sr[j], si[j]);
}

// ============ P2a: in-super serial scan, thread->ch coalesced (r5-proven) =====
__global__ __launch_bounds__(256) void p2a_kernel(
    float2* __restrict__ f, const float2* __restrict__ cAp, int lay) {
    int tg = blockIdx.x * 256 + threadIdx.x;    // 131072
    int ch = tg & 511;
    int ns = tg >> 9;
    int n = ns & 31, sup = ns >> 5;
    float2 ap = cAp[(lay * NST + n) * HD + ch];
    float2* fp = f + ((size_t)(sup * SUP) * NST + n) * HD + ch;
    float sr = 0.f, si = 0.f;
#pragma unroll
    for (int j = 0; j < SUP; ++j) {
        float2 v = fp[(size_t)j * NST * HD];
        float nr = fmaf(ap.x, sr, fmaf(-ap.y, si, v.x));
        float ni = fmaf(ap.y, sr, fmaf( ap.x, si, v.y));
        sr = nr; si = ni;
        fp[(size_t)j * NST * HD] = make_float2(sr, si);
    }
}

// ============ P2b: scan the 8 superchunk finals ============
__global__ __launch_bounds__(256) void p2b_kernel(
    float2* __restrict__ f, const float2* __restrict__ cAp, int lay) {
    int tg = blockIdx.x * 256 + threadIdx.x;    // 16384
    int ch = tg & 511, n = tg >> 9;
    float2 ap = cAp[(lay * NST + n) * HD + ch];
    float xr = ap.x, xi = ap.y;                 // ap^SUP (3 squarings)
#pragma unroll
    for (int q = 0; q < 3; ++q) { float tt = xr * xr - xi * xi; xi = 2.f * xr * xi; xr = tt; }
    float2* fp = f + ((size_t)(SUP - 1) * NST + n) * HD + ch;
    const size_t stride = (size_t)SUP * NST * HD;
    float sr = 0.f, si = 0.f;
#pragma unroll
    for (int k = 0; k < NSUP; ++k) {
        float2 v = fp[k * stride];
        float nr = fmaf(xr, sr, fmaf(-xi, si, v.x));
        float ni = fmaf(xi, sr, fmaf( xr, si, v.y));
        sr = nr; si = ni;
        fp[k * stride] = make_float2(sr, si);
    }
}

// ============ P2c: apply superchunk carry to j=0..SUP-2 of supers k>=1 ========
__global__ __launch_bounds__(256) void p2c_kernel(
    float2* __restrict__ f, const float2* __restrict__ cAp, int lay) {
    int tg = blockIdx.x * 256 + threadIdx.x;    // 131072
    int ch = tg & 511;
    int ns = tg >> 9;
    int n = ns & 31, sup = ns >> 5;
    if (sup == 0) return;
    float2 ap = cAp[(lay * NST + n) * HD + ch];
    float2 S = f[((size_t)(sup * SUP - 1) * NST + n) * HD + ch];
    float2* fp = f + ((size_t)(sup * SUP) * NST + n) * HD + ch;
    float wr = ap.x, wi = ap.y;
#pragma unroll
    for (int j = 0; j < SUP - 1; ++j) {
        float2 v = fp[(size_t)j * NST * HD];
        v.x += wr * S.x - wi * S.y;
        v.y += wr * S.y + wi * S.x;
        fp[(size_t)j * NST * HD] = v;
        float nwr = wr * ap.x - wi * ap.y;
        float nwi = wr * ap.y + wi * ap.x;
        wr = nwr; wi = nwi;
    }
}

// ============ P3: replay, LN on the fly, emit gelu(y) bf16. 1024 blocks =======
__global__ __launch_bounds__(256) void p3_kernel(
    const float* __restrict__ h, const float* __restrict__ st,
    const float2* __restrict__ f,
    const float2* __restrict__ cA, const float2* __restrict__ cB,
    const float2* __restrict__ cC, const float* __restrict__ dd,
    const float* __restrict__ nw, const float* __restrict__ nb,
    bf16* __restrict__ g, int lay) {
    __shared__ float  tile[4 * LC * 8];
    __shared__ float2 sml[128];
    __shared__ float  snw[8], snb[8];
    int tid = threadIdx.x;
    int lane = tid & 63, w = tid >> 6;
    int chl = lane & 7;
    int ch = blockIdx.x * 8 + chl;
    int sub = lane >> 3;
    int chunk = blockIdx.y * 4 + w;
    int t0 = blockIdx.y * 4 * LC;
    const float* ub = h + (size_t)t0 * HD + blockIdx.x * 8;
#pragma unroll
    for (int r = 0; r < 4; ++r) {
        int idx = r * 256 + tid;
        tile[idx] = ub[(idx >> 3) * HD + (idx & 7)];
    }
    if (tid < 128) {
        float s1 = st[(t0 + tid) * 2], s2 = st[(t0 + tid) * 2 + 1];
        float m = s1 * (1.f / HD);
        float var = s2 * (1.f / HD) - m * m;
        sml[tid] = make_float2(m, rsqrtf(var + 1e-5f));
    }
    if (tid < 8) {
        snw[tid] = nw[lay * HD + blockIdx.x * 8 + tid];
        snb[tid] = nb[lay * HD + blockIdx.x * 8 + tid];
    }
    int cbase = (lay * NST + sub * 4) * HD + ch;
    float aR[4], aI[4], bR[4], bI[4], cR[4], cI[4];
#pragma unroll
    for (int j = 0; j < 4; ++j) {
        float2 t = cA[cbase + j * HD]; aR[j] = t.x; aI[j] = t.y;
        t = cB[cbase + j * HD];        bR[j] = t.x; bI[j] = t.y;
        t = cC[cbase + j * HD];        cR[j] = t.x; cI[j] = t.y;
    }
    float dch = dd[lay * HD + ch];
    float sr[4], si[4];
    if (chunk > 0) {
        const float2* ip = f + ((size_t)(chunk - 1) * NST + sub * 4) * HD + ch;
#pragma unroll
        for (int j = 0; j < 4; ++j) { float2 v = ip[j * HD]; sr[j] = v.x; si[j] = v.y; }
    } else {
#pragma unroll
        for (int j = 0; j < 4; ++j) { sr[j] = 0.f; si[j] = 0.f; }
    }
    __syncthreads();
    float wch = snw[chl], bch = snb[chl];
    bf16* gp = g + (size_t)t0 * HD + ch;
#pragma unroll 4
    for (int t = 0; t < LC; ++t) {
        int row = w * LC + t;
        float2 ms = sml[row];
        float uu = (tile[row * 8 + chl] - ms.x) * ms.y * wch + bch;
        float p0 = 0.f, p1 = 0.f;
#pragma unroll
        for (int j = 0; j < 4; ++j) {
            float nr = fmaf(aR[j], sr[j], fmaf(-aI[j], si[j], bR[j] * uu));
            float ni = fmaf(aI[j], sr[j], fmaf( aR[j], si[j], bI[j] * uu));
            sr[j] = nr; si[j] = ni;
            p0 = fmaf(cR[j], nr, p0);
            p1 = fmaf(-cI[j], ni, p1);
        }
        float p = p0 + p1;
        p += __shfl_xor(p, 8);
        p += __shfl_xor(p, 16);
        p += __shfl_xor(p, 32);
        float y = fmaf(dch, uu, p);
        if (sub == 0) gp[(size_t)row * HD] = (bf16)gelu_tanh(y);
    }
}

// ============ mm: gated dual-matmul + residual + NEXT layer's LN-stat atomics ==
__global__ __launch_bounds__(256) void mm_kernel(
    const bf16* __restrict__ A,
    const bf16* __restrict__ W1,
    const bf16* __restrict__ W2,
    const float* __restrict__ bias1, const float* __restrict__ bias2,
    float* __restrict__ Hio, float* __restrict__ stn) {
    const int w = threadIdx.x >> 6, lane = threadIdx.x & 63;
    const int wm = w >> 1, wn = w & 1;
    const int mBase = blockIdx.y * 64 + wm * 32;
    const int nBase = blockIdx.x * 64 + wn * 32;
    const int lrow = lane & 15, quad = lane >> 4;

    floatx4 acc1[2][2] = {{{0.f,0.f,0.f,0.f},{0.f,0.f,0.f,0.f}},{{0.f,0.f,0.f,0.f},{0.f,0.f,0.f,0.f}}};
    floatx4 acc2[2][2] = {{{0.f,0.f,0.f,0.f},{0.f,0.f,0.f,0.f}},{{0.f,0.f,0.f,0.f},{0.f,0.f,0.f,0.f}}};

    for (int k0 = 0; k0 < HD; k0 += 32) {
        int kk = k0 + quad * 8;
        bf16x8 a0 = *(const bf16x8*)(A + (mBase + lrow) * HD + kk);
        bf16x8 a1 = *(const bf16x8*)(A + (mBase + 16 + lrow) * HD + kk);
        bf16x8 p0 = *(const bf16x8*)(W1 + (nBase + lrow) * HD + kk);
        bf16x8 p1 = *(const bf16x8*)(W1 + (nBase + 16 + lrow) * HD + kk);
        bf16x8 q0 = *(const bf16x8*)(W2 + (nBase + lrow) * HD + kk);
        bf16x8 q1 = *(const bf16x8*)(W2 + (nBase + 16 + lrow) * HD + kk);
        acc1[0][0] = __builtin_amdgcn_mfma_f32_16x16x32_bf16(a0, p0, acc1[0][0], 0, 0, 0);
        acc1[0][1] = __builtin_amdgcn_mfma_f32_16x16x32_bf16(a0, p1, acc1[0][1], 0, 0, 0);
        acc1[1][0] = __builtin_amdgcn_mfma_f32_16x16x32_bf16(a1, p0, acc1[1][0], 0, 0, 0);
        acc1[1][1] = __builtin_amdgcn_mfma_f32_16x16x32_bf16(a1, p1, acc1[1][1], 0, 0, 0);
        acc2[0][0] = __builtin_amdgcn_mfma_f32_16x16x32_bf16(a0, q0, acc2[0][0], 0, 0, 0);
        acc2[0][1] = __builtin_amdgcn_mfma_f32_16x16x32_bf16(a0, q1, acc2[0][1], 0, 0, 0);
        acc2[1][0] = __builtin_amdgcn_mfma_f32_16x16x32_bf16(a1, q0, acc2[1][0], 0, 0, 0);
        acc2[1][1] = __builtin_amdgcn_mfma_f32_16x16x32_bf16(a1, q1, acc2[1][1], 0, 0, 0);
    }

    float hv[2][2][4];
#pragma unroll
    for (int fm = 0; fm < 2; ++fm)
#pragma unroll
        for (int fn = 0; fn < 2; ++fn) {
            int j = nBase + fn * 16 + lrow;
            float bb1 = bias1[j], bb2 = bias2[j];
#pragma unroll
            for (int r = 0; r < 4; ++r) {
                int t = mBase + fm * 16 + quad * 4 + r;
                float z1 = acc1[fm][fn][r] + bb1;
                float z2 = acc2[fm][fn][r] + bb2;
                float nv = Hio[t * HD + j] + z1 / (1.f + __expf(-z2));
                Hio[t * HD + j] = nv;
                hv[fm][fn][r] = nv;
            }
        }
    // accumulate next layer's LN stats (sum, sumsq per row; 8 col-blocks/row)
#pragma unroll
    for (int fm = 0; fm < 2; ++fm)
#pragma unroll
        for (int r = 0; r < 4; ++r) {
            int t = mBase + fm * 16 + quad * 4 + r;
            float s1 = hv[fm][0][r] + hv[fm][1][r];
            float s2 = hv[fm][0][r] * hv[fm][0][r] + hv[fm][1][r] * hv[fm][1][r];
#pragma unroll
            for (int m = 1; m < 16; m <<= 1) {
                s1 += __shfl_xor(s1, m);
                s2 += __shfl_xor(s2, m);
            }
            if (lrow == 0) {
                atomicAdd(&stn[t * 2],     s1);
                atomicAdd(&stn[t * 2 + 1], s2);
            }
        }
}

// ============ decoder ============
__global__ __launch_bounds__(192) void dec_kernel(
    const float* __restrict__ h, const float* __restrict__ w,
    const float* __restrict__ b, float* __restrict__ out) {
    int j = threadIdx.x >> 6, lane = threadIdx.x & 63;
    int t = blockIdx.x;
    const float* hp = h + t * HD + lane * 8;
    float v[8];
    *(float4*)(v)     = *(const float4*)(hp);
    *(float4*)(v + 4) = *(const float4*)(hp + 4);
    float w8[8];
    *(float4*)(w8)     = *(const float4*)(w + j * HD + lane * 8);
    *(float4*)(w8 + 4) = *(const float4*)(w + j * HD + lane * 8 + 4);
    float s = 0.f;
#pragma unroll
    for (int e = 0; e < 8; ++e) s = fmaf(v[e], w8[e], s);
    s = wave_reduce_add(s);
    if (lane == 0) out[t * 3 + j] = s + b[j];
}

extern "C" void kernel_launch(void* const* d_in, const int* in_sizes, int n_in,
                              void* d_out, int out_size, void* d_ws, size_t ws_size,
                              hipStream_t stream) {
    const float* x   = (const float*)d_in[0];
    const float* ew  = (const float*)d_in[1];
    const float* eb  = (const float*)d_in[2];
    const float* dw  = (const float*)d_in[3];
    const float* db  = (const float*)d_in[4];
    const float* nw  = (const float*)d_in[5];
    const float* nb  = (const float*)d_in[6];
    const float* lre = (const float*)d_in[7];
    const float* lim = (const float*)d_in[8];
    const float* bre = (const float*)d_in[9];
    const float* bim = (const float*)d_in[10];
    const float* cre = (const float*)d_in[11];
    const float* cim = (const float*)d_in[12];
    const float* dd  = (const float*)d_in[13];
    const float* ls  = (const float*)d_in[14];
    const float* ow  = (const float*)d_in[15];
    const float* ob  = (const float*)d_in[16];
    const float* o2w = (const float*)d_in[17];
    const float* o2b = (const float*)d_in[18];
    char* ws = (char*)d_ws;

    float*  h     = (float*)ws;                           // 4 MB  [L][HD]
    float2* f     = (float2*)(ws + (4  << 20));           // 8 MB  [NCHK][NST][HD]
    bf16*   g     = (bf16*)(ws + (12 << 20));             // 2 MB  [L][HD] bf16
    bf16*   wb    = (bf16*)(ws + (14 << 20));             // 4 MB  bf16 weights
    float*  stats = (float*)(ws + (18 << 20));            // 5 x 2048 x 2 f32 = 80 KB
    float2* cA    = (float2*)(ws + (19 << 20));           // 4 x 512 KB
    float2* cB    = cA + 4 * NST * HD;
    float2* cC    = cB + 4 * NST * HD;
    float2* cAp   = cC + 4 * NST * HD;

    hipMemsetAsync(stats, 0, 5 * LSEQ * 2 * sizeof(float), stream);
    setup_kernel<<<4864, 256, 0, stream>>>(x, ew, eb, lre, lim, bre, bim,
                                           cre, cim, ls, ow, o2w,
                                           h, wb, cA, cB, cC, cAp, stats);
    for (int lay = 0; lay < 4; ++lay) {
        float* st  = stats + lay * LSEQ * 2;
        float* stn = stats + (lay + 1) * LSEQ * 2;
        p1_kernel<<<dim3(64, 16), 256, 0, stream>>>(h, st, cA, cB, nw, nb, f, lay);
        p2a_kernel<<<512, 256, 0, stream>>>(f, cAp, lay);
        p2b_kernel<<<64, 256, 0, stream>>>(f, cAp, lay);
        p2c_kernel<<<512, 256, 0, stream>>>(f, cAp, lay);
        p3_kernel<<<dim3(64, 16), 256, 0, stream>>>(h, st, f, cA, cB, cC, dd, nw, nb, g, lay);
        mm_kernel<<<dim3(8, 32), 256, 0, stream>>>(
            g, wb + lay * HH, wb + 4 * HH + lay * HH,
            ob + lay * HD, o2b + lay * HD, h, stn);
    }
    dec_kernel<<<LSEQ, 192, 0, stream>>>(h, dw, db, (float*)d_out);
}